// Round 4
// baseline (434.296 us; speedup 1.0000x reference)
//
#include <hip/hip_runtime.h>
#include <hip/hip_bf16.h>
#include <hip/hip_fp16.h>

// SkipGramNS: out[i] = dot(cxt_weight[ctx[i]], tgt_weight[tgt[i]]), D=128.
// R4: gather time ∝ L2-miss bytes @ ~3.45 TB/s (measured R0-R3). Cut ctx-side
// misses by counting-sorting pairs by ctx bucket (ctx>>7 ≈ 32 KB fp16/bucket)
// so each ctx row's ~10 uses are temporally adjacent and L2-resident. XCD
// swizzle gives each XCD a contiguous (disjoint-ctx) slice of sorted pairs so
// ctx rows are not duplicated across 8 per-XCD L2s.

#define D 128
#define BSHIFT 7
#define NB 1024   // bucket slots (V/128 = 782 used for V=100000)

typedef _Float16 half8_t __attribute__((ext_vector_type(8)));

// ---- fp32 -> fp16 table conversion (streaming); last block zeroes hist ----
__global__ __launch_bounds__(256) void convert_fp16_kernel(
    const float* __restrict__ cxt_w, const float* __restrict__ tgt_w,
    _Float16* __restrict__ cxt_h, _Float16* __restrict__ tgt_h,
    int elems_per_table, unsigned* __restrict__ hist, int conv_grid)
{
    if ((int)blockIdx.x == conv_grid) {   // dedicated zero block (runs before hist_kernel: stream order)
        for (int i = threadIdx.x; i < NB; i += 256) hist[i] = 0u;
        return;
    }
    const int per_table_thr = elems_per_table >> 3;   // 8 floats per thread
    const int tid = blockIdx.x * blockDim.x + threadIdx.x;

    const float* src;
    _Float16* dst;
    int off;
    if (tid < per_table_thr) {
        src = cxt_w; dst = cxt_h; off = tid << 3;
    } else if (tid < 2 * per_table_thr) {
        src = tgt_w; dst = tgt_h; off = (tid - per_table_thr) << 3;
    } else {
        return;
    }

    const float4 a = *reinterpret_cast<const float4*>(src + off);
    const float4 b = *reinterpret_cast<const float4*>(src + off + 4);
    half8_t h;
    h[0] = (_Float16)a.x; h[1] = (_Float16)a.y;
    h[2] = (_Float16)a.z; h[3] = (_Float16)a.w;
    h[4] = (_Float16)b.x; h[5] = (_Float16)b.y;
    h[6] = (_Float16)b.z; h[7] = (_Float16)b.w;
    *reinterpret_cast<half8_t*>(dst + off) = h;
}

// ---- histogram of ctx buckets (LDS-local then flush) ----
__global__ __launch_bounds__(256) void hist_kernel(
    const int* __restrict__ ctx, int n, unsigned* __restrict__ hist)
{
    __shared__ unsigned lh[NB];
    for (int i = threadIdx.x; i < NB; i += 256) lh[i] = 0u;
    __syncthreads();
    for (long long i = blockIdx.x * 256ll + threadIdx.x; i < n;
         i += (long long)gridDim.x * 256)
        atomicAdd(&lh[ctx[i] >> BSHIFT], 1u);
    __syncthreads();
    for (int i = threadIdx.x; i < NB; i += 256) {
        unsigned v = lh[i];
        if (v) atomicAdd(&hist[i], v);
    }
}

// ---- exclusive scan of NB counters -> cursor ----
__global__ __launch_bounds__(1024) void scan_kernel(
    const unsigned* __restrict__ hist, unsigned* __restrict__ cursor)
{
    __shared__ unsigned s[NB];
    const int t = threadIdx.x;
    const unsigned own = hist[t];
    s[t] = own;
    __syncthreads();
    #pragma unroll
    for (int off = 1; off < NB; off <<= 1) {
        unsigned add = (t >= off) ? s[t - off] : 0u;
        __syncthreads();
        s[t] += add;
        __syncthreads();
    }
    cursor[t] = s[t] - own;   // exclusive
}

// ---- scatter pairs into ctx-bucket-sorted order ----
__global__ __launch_bounds__(256) void scatter_kernel(
    const int* __restrict__ ctx, const int* __restrict__ tgt, int n,
    unsigned* __restrict__ cursor,
    int* __restrict__ sctx, int* __restrict__ stgt, int* __restrict__ sid)
{
    const long long i = blockIdx.x * 256ll + threadIdx.x;
    if (i >= n) return;
    const int c = ctx[i];
    const int t = tgt[i];
    const unsigned pos = atomicAdd(&cursor[c >> BSHIFT], 1u);
    sctx[pos] = c;
    stgt[pos] = t;
    sid[pos] = (int)i;
}

// ---- sorted fp16 gather + dot; 16 lanes/pair, 4 pairs/group, XCD swizzle ----
__global__ __launch_bounds__(256) void gather_dot_sorted_kernel(
    const int* __restrict__ sctx, const int* __restrict__ stgt,
    const int* __restrict__ sid,
    const _Float16* __restrict__ cxt_h, const _Float16* __restrict__ tgt_h,
    float* __restrict__ out, int n, int nlogical)
{
    // blocks round-robin XCDs (b%8); give each XCD a CONTIGUOUS slice of the
    // sorted pair stream so its L2 caches a disjoint ctx-row range.
    const int chunks = (nlogical + 7) >> 3;
    const int lb = (int)(blockIdx.x & 7) * chunks + (int)(blockIdx.x >> 3);
    if (lb >= nlogical) return;

    const int lane = threadIdx.x & 15;
    const int grp  = threadIdx.x >> 4;          // 16 groups/block
    const int p0 = lb * 64 + grp * 4;           // 4 pairs per group
    if (p0 >= n) return;

    if (p0 + 4 <= n) {
        const int4 ci4 = *reinterpret_cast<const int4*>(sctx + p0);
        const int4 ti4 = *reinterpret_cast<const int4*>(stgt + p0);
        const int4 id4 = *reinterpret_cast<const int4*>(sid + p0);
        const int ci[4] = {ci4.x, ci4.y, ci4.z, ci4.w};
        const int ti[4] = {ti4.x, ti4.y, ti4.z, ti4.w};

        half8_t c[4], t[4];
        #pragma unroll
        for (int u = 0; u < 4; ++u) {
            c[u] = *reinterpret_cast<const half8_t*>(cxt_h + (size_t)ci[u] * D + lane * 8);
            t[u] = *reinterpret_cast<const half8_t*>(tgt_h + (size_t)ti[u] * D + lane * 8);
        }

        float p[4];
        #pragma unroll
        for (int u = 0; u < 4; ++u) {
            float s = 0.f;
            #pragma unroll
            for (int k = 0; k < 8; ++k)
                s = fmaf((float)c[u][k], (float)t[u][k], s);
            p[u] = s;
        }
        #pragma unroll
        for (int u = 0; u < 4; ++u) {
            p[u] += __shfl_xor(p[u], 8);
            p[u] += __shfl_xor(p[u], 4);
            p[u] += __shfl_xor(p[u], 2);
            p[u] += __shfl_xor(p[u], 1);
        }
        if (lane == 0) {
            out[id4.x] = p[0];
            out[id4.y] = p[1];
            out[id4.z] = p[2];
            out[id4.w] = p[3];
        }
    } else {
        for (int u = 0; u < 4 && p0 + u < n; ++u) {
            const int pi = p0 + u;
            const int cidx = sctx[pi];
            const int tidx = stgt[pi];
            const half8_t c = *reinterpret_cast<const half8_t*>(cxt_h + (size_t)cidx * D + lane * 8);
            const half8_t t = *reinterpret_cast<const half8_t*>(tgt_h + (size_t)tidx * D + lane * 8);
            float s = 0.f;
            #pragma unroll
            for (int k = 0; k < 8; ++k)
                s = fmaf((float)c[k], (float)t[k], s);
            s += __shfl_xor(s, 8);
            s += __shfl_xor(s, 4);
            s += __shfl_xor(s, 2);
            s += __shfl_xor(s, 1);
            if (lane == 0) out[sid[pi]] = s;
        }
    }
}

// ---- fallback: unsorted fp16 gather (R3) ----
__global__ __launch_bounds__(256) void gather_dot_h_kernel(
    const int* __restrict__ ctx_idx, const int* __restrict__ tgt_idx,
    const _Float16* __restrict__ cxt_h, const _Float16* __restrict__ tgt_h,
    float* __restrict__ out, int n)
{
    const int lane = threadIdx.x & 15;
    const long long g = ((long long)blockIdx.x * blockDim.x + threadIdx.x) >> 4;
    const int p0 = (int)(g << 2);
    if (p0 >= n) return;
    for (int u = 0; u < 4 && p0 + u < n; ++u) {
        const int pi = p0 + u;
        const half8_t c = *reinterpret_cast<const half8_t*>(cxt_h + (size_t)ctx_idx[pi] * D + lane * 8);
        const half8_t t = *reinterpret_cast<const half8_t*>(tgt_h + (size_t)tgt_idx[pi] * D + lane * 8);
        float s = 0.f;
        #pragma unroll
        for (int k = 0; k < 8; ++k)
            s = fmaf((float)c[k], (float)t[k], s);
        s += __shfl_xor(s, 8);
        s += __shfl_xor(s, 4);
        s += __shfl_xor(s, 2);
        s += __shfl_xor(s, 1);
        if (lane == 0) out[pi] = s;
    }
}

// ---- fallback: fp32 direct (no ws) ----
__global__ __launch_bounds__(256) void gather_dot_f32_kernel(
    const int* __restrict__ ctx_idx, const int* __restrict__ tgt_idx,
    const float* __restrict__ cxt_w, const float* __restrict__ tgt_w,
    float* __restrict__ out, int n)
{
    const int lane = threadIdx.x & 31;
    const long long g = ((long long)blockIdx.x * blockDim.x + threadIdx.x) >> 5;
    const int pair = (int)g;
    if (pair >= n) return;
    const float4 c = reinterpret_cast<const float4*>(cxt_w + (size_t)ctx_idx[pair] * D)[lane];
    const float4 t = reinterpret_cast<const float4*>(tgt_w + (size_t)tgt_idx[pair] * D)[lane];
    float s = c.x * t.x;
    s = fmaf(c.y, t.y, s);
    s = fmaf(c.z, t.z, s);
    s = fmaf(c.w, t.w, s);
    s += __shfl_xor(s, 16);
    s += __shfl_xor(s, 8);
    s += __shfl_xor(s, 4);
    s += __shfl_xor(s, 2);
    s += __shfl_xor(s, 1);
    if (lane == 0) out[pair] = s;
}

extern "C" void kernel_launch(void* const* d_in, const int* in_sizes, int n_in,
                              void* d_out, int out_size, void* d_ws, size_t ws_size,
                              hipStream_t stream) {
    const int*   ctx_idx = (const int*)d_in[0];
    const int*   tgt_idx = (const int*)d_in[1];
    const float* cxt_w   = (const float*)d_in[2];
    const float* tgt_w   = (const float*)d_in[3];
    float*       out     = (float*)d_out;

    const int n = in_sizes[0];            // N pairs
    const int elems = in_sizes[2];        // V*D per table

    const size_t tab_bytes = (size_t)elems * sizeof(_Float16);
    const size_t need_fp16 = 2 * tab_bytes;
    const size_t need_sorted = need_fp16 + 2 * NB * sizeof(unsigned) + 3 * (size_t)n * sizeof(int) + 256;

    if (ws_size >= need_sorted) {
        char* p = (char*)d_ws;
        _Float16* cxt_h = (_Float16*)p;            p += tab_bytes;
        _Float16* tgt_h = (_Float16*)p;            p += tab_bytes;
        unsigned* hist   = (unsigned*)p;           p += NB * sizeof(unsigned);
        unsigned* cursor = (unsigned*)p;           p += NB * sizeof(unsigned);
        int* sctx = (int*)p;                       p += (size_t)n * sizeof(int);
        int* stgt = (int*)p;                       p += (size_t)n * sizeof(int);
        int* sid  = (int*)p;

        const int conv_grid = ((elems >> 3) * 2 + 255) / 256;
        convert_fp16_kernel<<<conv_grid + 1, 256, 0, stream>>>(
            cxt_w, tgt_w, cxt_h, tgt_h, elems, hist, conv_grid);

        hist_kernel<<<128, 256, 0, stream>>>(ctx_idx, n, hist);
        scan_kernel<<<1, 1024, 0, stream>>>(hist, cursor);
        scatter_kernel<<<(n + 255) / 256, 256, 0, stream>>>(
            ctx_idx, tgt_idx, n, cursor, sctx, stgt, sid);

        const int nlogical = (n + 63) / 64;       // blocks of 64 pairs
        const int chunks = (nlogical + 7) >> 3;
        gather_dot_sorted_kernel<<<chunks * 8, 256, 0, stream>>>(
            sctx, stgt, sid, cxt_h, tgt_h, out, n, nlogical);
    } else if (ws_size >= need_fp16) {
        _Float16* cxt_h = (_Float16*)d_ws;
        _Float16* tgt_h = cxt_h + elems;
        const int conv_grid = ((elems >> 3) * 2 + 255) / 256;
        // no hist in this path: pass a dummy (never dereferenced because grid == conv_grid)
        convert_fp16_kernel<<<conv_grid, 256, 0, stream>>>(
            cxt_w, tgt_w, cxt_h, tgt_h, elems, (unsigned*)d_ws, conv_grid + 1);
        const int pairs_per_block = (256 / 16) * 4;
        gather_dot_h_kernel<<<(n + pairs_per_block - 1) / pairs_per_block, 256, 0, stream>>>(
            ctx_idx, tgt_idx, cxt_h, tgt_h, out, n);
    } else {
        gather_dot_f32_kernel<<<(n + 7) / 8, 256, 0, stream>>>(
            ctx_idx, tgt_idx, cxt_w, tgt_w, out, n);
    }
}

// Round 5
// 166.145 us; speedup vs baseline: 2.6140x; 2.6140x over previous
//
#include <hip/hip_runtime.h>
#include <hip/hip_bf16.h>
#include <hip/hip_fp16.h>

// SkipGramNS: out[i] = dot(cxt_weight[ctx[i]], tgt_weight[tgt[i]]), D=128.
// R5: revert R4's counting sort (scatter_kernel = 238 us of atomic serialization).
// Gather time scales linearly with gathered bytes (R2->R3: 0.5x bytes -> 0.48x
// time). Next notch: int8 rows with per-row fp32 scale. Row = 128 B (vs 256 fp16).
// Integer dot is exact in int32; only quantization noise (~1.6e-6 absmax predicted,
// threshold 5.57e-6). Demand drops 512 -> 256 MB; tables now 25.6 MB total.

#define D 128

// 4x int8 dot-accumulate. Prefer the HW sdot4 if available.
#if defined(__has_builtin)
#if __has_builtin(__builtin_amdgcn_sdot4)
#define HAVE_SDOT4 1
#endif
#endif

__device__ __forceinline__ int dot4_i8(int a, int b, int c) {
#ifdef HAVE_SDOT4
    return __builtin_amdgcn_sdot4(a, b, c, false);
#else
    c += ((a << 24) >> 24) * ((b << 24) >> 24);
    c += ((a << 16) >> 24) * ((b << 16) >> 24);
    c += ((a <<  8) >> 24) * ((b <<  8) >> 24);
    c += ( a        >> 24) * ( b        >> 24);
    return c;
#endif
}

// ---- Pass 1: fp32 rows -> int8 rows + per-row scale. 16 lanes/row, 8 elems/lane ----
__global__ __launch_bounds__(256) void convert_int8_kernel(
    const float* __restrict__ cxt_w, const float* __restrict__ tgt_w,
    signed char* __restrict__ cxt_q, signed char* __restrict__ tgt_q,
    float* __restrict__ cxt_s, float* __restrict__ tgt_s, int V)
{
    const int row  = blockIdx.x * 16 + (threadIdx.x >> 4);
    const int lane = threadIdx.x & 15;
    if (row >= 2 * V) return;

    const float* src; signed char* dq; float* ds; int r;
    if (row < V) { src = cxt_w; dq = cxt_q; ds = cxt_s; r = row; }
    else         { src = tgt_w; dq = tgt_q; ds = tgt_s; r = row - V; }

    const float4 a = *reinterpret_cast<const float4*>(src + (size_t)r * D + lane * 8);
    const float4 b = *reinterpret_cast<const float4*>(src + (size_t)r * D + lane * 8 + 4);

    float m = fabsf(a.x);
    m = fmaxf(m, fabsf(a.y)); m = fmaxf(m, fabsf(a.z)); m = fmaxf(m, fabsf(a.w));
    m = fmaxf(m, fabsf(b.x)); m = fmaxf(m, fabsf(b.y));
    m = fmaxf(m, fabsf(b.z)); m = fmaxf(m, fabsf(b.w));
    // row max across the 16-lane group (masks stay inside the group)
    m = fmaxf(m, __shfl_xor(m, 8));
    m = fmaxf(m, __shfl_xor(m, 4));
    m = fmaxf(m, __shfl_xor(m, 2));
    m = fmaxf(m, __shfl_xor(m, 1));

    const float inv = (m > 0.f) ? 127.f / m : 0.f;

    const float v[8] = {a.x, a.y, a.z, a.w, b.x, b.y, b.z, b.w};
    int q[8];
    #pragma unroll
    for (int k = 0; k < 8; ++k) {
        int t = (int)__builtin_rintf(v[k] * inv);
        t = t > 127 ? 127 : (t < -127 ? -127 : t);
        q[k] = t & 255;
    }
    int2 packed;
    packed.x = q[0] | (q[1] << 8) | (q[2] << 16) | (q[3] << 24);
    packed.y = q[4] | (q[5] << 8) | (q[6] << 16) | (q[7] << 24);
    *reinterpret_cast<int2*>(dq + (size_t)r * D + lane * 8) = packed;

    if (lane == 0) ds[r] = m * (1.f / 127.f);
}

// ---- Pass 2: int8 gather + exact int dot. 8 lanes/pair (8 x 16B = 128B row),
//      4 pairs per 8-lane group ----
__global__ __launch_bounds__(256) void gather_dot_q_kernel(
    const int* __restrict__ ctx_idx, const int* __restrict__ tgt_idx,
    const signed char* __restrict__ cxt_q, const signed char* __restrict__ tgt_q,
    const float* __restrict__ cxt_s, const float* __restrict__ tgt_s,
    float* __restrict__ out, int n)
{
    const int lane = threadIdx.x & 7;
    const long long g = ((long long)blockIdx.x * blockDim.x + threadIdx.x) >> 3;
    const int p0 = (int)(g << 2);
    if (p0 >= n) return;

    if (p0 + 4 <= n) {
        const int4 ci4 = *reinterpret_cast<const int4*>(ctx_idx + p0);
        const int4 ti4 = *reinterpret_cast<const int4*>(tgt_idx + p0);
        const int ci[4] = {ci4.x, ci4.y, ci4.z, ci4.w};
        const int ti[4] = {ti4.x, ti4.y, ti4.z, ti4.w};

        int4 qc[4], qt[4];
        #pragma unroll
        for (int u = 0; u < 4; ++u) {
            qc[u] = *reinterpret_cast<const int4*>(cxt_q + (size_t)ci[u] * D + lane * 16);
            qt[u] = *reinterpret_cast<const int4*>(tgt_q + (size_t)ti[u] * D + lane * 16);
        }
        float sc[4], st[4];
        #pragma unroll
        for (int u = 0; u < 4; ++u) { sc[u] = cxt_s[ci[u]]; st[u] = tgt_s[ti[u]]; }

        int acc[4];
        #pragma unroll
        for (int u = 0; u < 4; ++u) {
            int s = dot4_i8(qc[u].x, qt[u].x, 0);
            s = dot4_i8(qc[u].y, qt[u].y, s);
            s = dot4_i8(qc[u].z, qt[u].z, s);
            s = dot4_i8(qc[u].w, qt[u].w, s);
            acc[u] = s;
        }
        #pragma unroll
        for (int u = 0; u < 4; ++u) {
            acc[u] += __shfl_xor(acc[u], 4);
            acc[u] += __shfl_xor(acc[u], 2);
            acc[u] += __shfl_xor(acc[u], 1);
        }
        if (lane == 0) {
            *reinterpret_cast<float4*>(out + p0) = make_float4(
                (float)acc[0] * sc[0] * st[0],
                (float)acc[1] * sc[1] * st[1],
                (float)acc[2] * sc[2] * st[2],
                (float)acc[3] * sc[3] * st[3]);
        }
    } else {
        for (int u = 0; u < 4 && p0 + u < n; ++u) {
            const int pi = p0 + u;
            const int ci = ctx_idx[pi];
            const int ti = tgt_idx[pi];
            const int4 qc = *reinterpret_cast<const int4*>(cxt_q + (size_t)ci * D + lane * 16);
            const int4 qt = *reinterpret_cast<const int4*>(tgt_q + (size_t)ti * D + lane * 16);
            int s = dot4_i8(qc.x, qt.x, 0);
            s = dot4_i8(qc.y, qt.y, s);
            s = dot4_i8(qc.z, qt.z, s);
            s = dot4_i8(qc.w, qt.w, s);
            s += __shfl_xor(s, 4);
            s += __shfl_xor(s, 2);
            s += __shfl_xor(s, 1);
            if (lane == 0) out[pi] = (float)s * cxt_s[ci] * tgt_s[ti];
        }
    }
}

// ---- Fallback (ws too small): fp32 direct ----
__global__ __launch_bounds__(256) void gather_dot_f32_kernel(
    const int* __restrict__ ctx_idx, const int* __restrict__ tgt_idx,
    const float* __restrict__ cxt_w, const float* __restrict__ tgt_w,
    float* __restrict__ out, int n)
{
    const int lane = threadIdx.x & 31;
    const long long g = ((long long)blockIdx.x * blockDim.x + threadIdx.x) >> 5;
    const int pair = (int)g;
    if (pair >= n) return;
    const float4 c = reinterpret_cast<const float4*>(cxt_w + (size_t)ctx_idx[pair] * D)[lane];
    const float4 t = reinterpret_cast<const float4*>(tgt_w + (size_t)tgt_idx[pair] * D)[lane];
    float s = c.x * t.x;
    s = fmaf(c.y, t.y, s);
    s = fmaf(c.z, t.z, s);
    s = fmaf(c.w, t.w, s);
    s += __shfl_xor(s, 16);
    s += __shfl_xor(s, 8);
    s += __shfl_xor(s, 4);
    s += __shfl_xor(s, 2);
    s += __shfl_xor(s, 1);
    if (lane == 0) out[pair] = s;
}

extern "C" void kernel_launch(void* const* d_in, const int* in_sizes, int n_in,
                              void* d_out, int out_size, void* d_ws, size_t ws_size,
                              hipStream_t stream) {
    const int*   ctx_idx = (const int*)d_in[0];
    const int*   tgt_idx = (const int*)d_in[1];
    const float* cxt_w   = (const float*)d_in[2];
    const float* tgt_w   = (const float*)d_in[3];
    float*       out     = (float*)d_out;

    const int n = in_sizes[0];        // N pairs
    const int elems = in_sizes[2];    // V*D per table
    const int V = elems / D;

    const size_t qtab = (size_t)V * D;                    // bytes per int8 table
    const size_t need = 2 * qtab + 2 * (size_t)V * sizeof(float) + 64;

    if (ws_size >= need) {
        char* p = (char*)d_ws;
        signed char* cxt_q = (signed char*)p;  p += qtab;
        signed char* tgt_q = (signed char*)p;  p += qtab;
        float* cxt_s = (float*)p;              p += (size_t)V * sizeof(float);
        float* tgt_s = (float*)p;

        // Pass 1: quantize both tables (16 rows per block).
        const int conv_grid = (2 * V + 15) / 16;
        convert_int8_kernel<<<conv_grid, 256, 0, stream>>>(
            cxt_w, tgt_w, cxt_q, tgt_q, cxt_s, tgt_s, V);

        // Pass 2: gather + int8 dot. 8 lanes/pair, 4 pairs/group -> 128 pairs/block.
        const int pairs_per_block = (256 / 8) * 4;
        const int grid = (n + pairs_per_block - 1) / pairs_per_block;
        gather_dot_q_kernel<<<grid, 256, 0, stream>>>(
            ctx_idx, tgt_idx, cxt_q, tgt_q, cxt_s, tgt_s, out, n);
    } else {
        gather_dot_f32_kernel<<<(n + 7) / 8, 256, 0, stream>>>(
            ctx_idx, tgt_idx, cxt_w, tgt_w, out, n);
    }
}